// Round 12
// baseline (123.427 us; speedup 1.0000x reference)
//
#include <hip/hip_runtime.h>
#include <hip/hip_bf16.h>

namespace {

constexpr int D = 4096;
constexpr int NT = 256;

// Native clang vector type — the nontemporal builtins reject HIP's struct float4.
typedef float fvec4 __attribute__((ext_vector_type(4)));

// XOR swizzle on the logical dword index. Sources {bit5, bit8, bit9} are
// disjoint from targets {bit2, bit3, bit4} -> bijection (involution), result
// stays in [0, 4096). Bits [1:0] untouched -> 4-dword aligned quads remain
// contiguous, so b128 LDS ops survive.
// Bank math (bank = dword addr mod 32):
//  R1 write (i = 16t+4q+c): quad bank-group (t0^t4, q1^t5, q0^t1)
//      -> uniform 8 lanes/group (optimal b128).
//  R2 r/w  (i = 256a+16k+b): bank = (k0^a0, b3^a1, b2^k1, b1, b0) -> 2-way, free.
//  R3 r/w  (i = 256k+t):    bank = (t4^k0, t3^k1, t2^t5, t1, t0) -> 2-way, free.
//  R4 read (i = 4t+1024m+c): quad bank-group (t2^t6, t1^t7, t0^t3)
//      -> uniform 8 lanes/group (optimal b128).
__device__ __forceinline__ int swz(int i) {
    return i ^ (((i >> 8) & 1) << 4) ^ (((i >> 9) & 1) << 3) ^ (((i >> 5) & 1) << 2);
}

__device__ __forceinline__ void fwht16(float v[16]) {
#pragma unroll
    for (int h = 1; h < 16; h <<= 1) {
#pragma unroll
        for (int g = 0; g < 16; g += (h << 1)) {
#pragma unroll
            for (int j = 0; j < h; ++j) {
                const float a = v[g + j];
                const float b = v[g + j + h];
                v[g + j] = a + b;
                v[g + j + h] = a - b;
            }
        }
    }
}

__global__ __launch_bounds__(NT) void rht_kernel(const float* __restrict__ x,
                                                 const float* __restrict__ signs,
                                                 float* __restrict__ out) {
    __shared__ float lds[D];  // 16 KiB
    const int t = threadIdx.x;
    const size_t row = blockIdx.x;
    const float* __restrict__ xr = x + row * (size_t)D;
    float* __restrict__ outr = out + row * (size_t)D;

    float v[16];

    // ---- Round 1: thread owns i = 16t + k (bits 0-3). NONTEMPORAL float4
    // loads for the read-once x stream (full 64B lines per wave, evict-first);
    // signs stays normally cached (reused by every block).
    {
        const fvec4* __restrict__ x4 = reinterpret_cast<const fvec4*>(xr) + (t << 2);
        const float4* __restrict__ s4 = reinterpret_cast<const float4*>(signs) + (t << 2);
#pragma unroll
        for (int q = 0; q < 4; ++q) {
            const fvec4 a = __builtin_nontemporal_load(&x4[q]);
            const float4 s = s4[q];
            v[4 * q + 0] = a.x * s.x;
            v[4 * q + 1] = a.y * s.y;
            v[4 * q + 2] = a.z * s.z;
            v[4 * q + 3] = a.w * s.w;
        }
    }
    fwht16(v);
#pragma unroll
    for (int q = 0; q < 4; ++q) {
        *reinterpret_cast<float4*>(&lds[swz((t << 4) + (q << 2))]) =
            make_float4(v[4 * q], v[4 * q + 1], v[4 * q + 2], v[4 * q + 3]);
    }
    __syncthreads();

    // ---- Round 2: thread owns i = (t>>4)*256 + 16k + (t&15) (bits 4-7).
    // Same-thread read+write of its own 16 slots -> no barrier inside.
    {
        const int b2 = ((t >> 4) << 8) + (t & 15);
#pragma unroll
        for (int k = 0; k < 16; ++k) v[k] = lds[swz(b2 + (k << 4))];
        fwht16(v);
#pragma unroll
        for (int k = 0; k < 16; ++k) lds[swz(b2 + (k << 4))] = v[k];
    }
    __syncthreads();

    // ---- Round 3: thread owns i = 256k + t (bits 8-11). Results go back to
    // LDS (same slots, same thread) so R4 can store vectorized.
    {
#pragma unroll
        for (int k = 0; k < 16; ++k) v[k] = lds[swz((k << 8) + t)];
        fwht16(v);
#pragma unroll
        for (int k = 0; k < 16; ++k) lds[swz((k << 8) + t)] = v[k];
    }
    __syncthreads();

    // ---- Round 4: regroup to contiguous quads (i = 4t + 1024m), b128 LDS
    // reads; NONTEMPORAL float4 stores (full 64B lines per wave, evict-first
    // in L2 so the write stream doesn't evict inbound read lines).
#pragma unroll
    for (int m = 0; m < 4; ++m) {
        float4 w = *reinterpret_cast<const float4*>(&lds[swz((t << 2) + (m << 10))]);
        fvec4 o;
        o.x = w.x * 0.015625f;  // 1/sqrt(4096)
        o.y = w.y * 0.015625f;
        o.z = w.z * 0.015625f;
        o.w = w.w * 0.015625f;
        __builtin_nontemporal_store(o,
            reinterpret_cast<fvec4*>(&outr[(t << 2) + (m << 10)]));
    }
}

}  // namespace

extern "C" void kernel_launch(void* const* d_in, const int* in_sizes, int n_in,
                              void* d_out, int out_size, void* d_ws, size_t ws_size,
                              hipStream_t stream) {
    const float* x = (const float*)d_in[0];
    const float* signs = (const float*)d_in[1];
    float* out = (float*)d_out;
    const int B = in_sizes[0] / D;  // 16384 rows
    rht_kernel<<<dim3(B), dim3(NT), 0, stream>>>(x, signs, out);
}

// Round 13
// 80.190 us; speedup vs baseline: 1.5392x; 1.5392x over previous
//
#include <hip/hip_runtime.h>
#include <hip/hip_bf16.h>

namespace {

constexpr int D = 4096;
constexpr int NT = 256;

// Native clang vector type — the nontemporal builtins reject HIP's struct float4.
typedef float fvec4 __attribute__((ext_vector_type(4)));

// XOR swizzle on the logical dword index. Sources {bit5, bit8, bit9} are
// disjoint from targets {bit2, bit3, bit4} -> bijection (involution), result
// stays in [0, 4096). Bits [1:0] untouched -> 4-dword aligned quads remain
// contiguous, so b128 LDS ops survive.
// Bank math (bank = dword addr mod 32):
//  R1 write (i = 16t+4q+c): quad bank-group (t0^t4, q1^t5, q0^t1)
//      -> uniform 8 lanes/group (optimal b128).
//  R2 r/w  (i = 256a+16k+b): bank = (k0^a0, b3^a1, b2^k1, b1, b0) -> 2-way, free.
//  R3 r/w  (i = 256k+t):    bank = (t4^k0, t3^k1, t2^t5, t1, t0) -> 2-way, free.
//  R4 read (i = 4t+1024m+c): quad bank-group (t2^t6, t1^t7, t0^t3)
//      -> uniform 8 lanes/group (optimal b128).
//
// Session ledger (measured):
//  - nt STORES (full 64B lines): +20% — write stream stops polluting L2.
//  - nt LOADS: −54% — read stream needs normal L2 allocation (in-flight
//    line reuse across waves). Never nt the load side of a stream.
//  - scalar nt stores (R3): −37% — partial-line evict-first write-amplifies.
__device__ __forceinline__ int swz(int i) {
    return i ^ (((i >> 8) & 1) << 4) ^ (((i >> 9) & 1) << 3) ^ (((i >> 5) & 1) << 2);
}

__device__ __forceinline__ void fwht16(float v[16]) {
#pragma unroll
    for (int h = 1; h < 16; h <<= 1) {
#pragma unroll
        for (int g = 0; g < 16; g += (h << 1)) {
#pragma unroll
            for (int j = 0; j < h; ++j) {
                const float a = v[g + j];
                const float b = v[g + j + h];
                v[g + j] = a + b;
                v[g + j + h] = a - b;
            }
        }
    }
}

__global__ __launch_bounds__(NT) void rht_kernel(const float* __restrict__ x,
                                                 const float* __restrict__ signs,
                                                 float* __restrict__ out) {
    __shared__ float lds[D];  // 16 KiB
    const int t = threadIdx.x;
    const size_t row = blockIdx.x;
    const float* __restrict__ xr = x + row * (size_t)D;
    float* __restrict__ outr = out + row * (size_t)D;

    float v[16];

    // ---- Round 1: thread owns i = 16t + k (bits 0-3). Cached float4 loads,
    // 1 KiB contiguous per wave instruction.
    {
        const float4* __restrict__ x4 = reinterpret_cast<const float4*>(xr) + (t << 2);
        const float4* __restrict__ s4 = reinterpret_cast<const float4*>(signs) + (t << 2);
#pragma unroll
        for (int q = 0; q < 4; ++q) {
            const float4 a = x4[q];
            const float4 s = s4[q];
            v[4 * q + 0] = a.x * s.x;
            v[4 * q + 1] = a.y * s.y;
            v[4 * q + 2] = a.z * s.z;
            v[4 * q + 3] = a.w * s.w;
        }
    }
    fwht16(v);
#pragma unroll
    for (int q = 0; q < 4; ++q) {
        *reinterpret_cast<float4*>(&lds[swz((t << 4) + (q << 2))]) =
            make_float4(v[4 * q], v[4 * q + 1], v[4 * q + 2], v[4 * q + 3]);
    }
    __syncthreads();

    // ---- Round 2: thread owns i = (t>>4)*256 + 16k + (t&15) (bits 4-7).
    // Same-thread read+write of its own 16 slots -> no barrier inside.
    {
        const int b2 = ((t >> 4) << 8) + (t & 15);
#pragma unroll
        for (int k = 0; k < 16; ++k) v[k] = lds[swz(b2 + (k << 4))];
        fwht16(v);
#pragma unroll
        for (int k = 0; k < 16; ++k) lds[swz(b2 + (k << 4))] = v[k];
    }
    __syncthreads();

    // ---- Round 3: thread owns i = 256k + t (bits 8-11). Results go back to
    // LDS (same slots, same thread) so R4 can store vectorized.
    {
#pragma unroll
        for (int k = 0; k < 16; ++k) v[k] = lds[swz((k << 8) + t)];
        fwht16(v);
#pragma unroll
        for (int k = 0; k < 16; ++k) lds[swz((k << 8) + t)] = v[k];
    }
    __syncthreads();

    // ---- Round 4: regroup to contiguous quads (i = 4t + 1024m), b128 LDS
    // reads; NONTEMPORAL float4 stores (full 64B lines per wave, evict-first
    // in L2 so the write stream doesn't evict inbound read lines).
#pragma unroll
    for (int m = 0; m < 4; ++m) {
        float4 w = *reinterpret_cast<const float4*>(&lds[swz((t << 2) + (m << 10))]);
        fvec4 o;
        o.x = w.x * 0.015625f;  // 1/sqrt(4096)
        o.y = w.y * 0.015625f;
        o.z = w.z * 0.015625f;
        o.w = w.w * 0.015625f;
        __builtin_nontemporal_store(o,
            reinterpret_cast<fvec4*>(&outr[(t << 2) + (m << 10)]));
    }
}

}  // namespace

extern "C" void kernel_launch(void* const* d_in, const int* in_sizes, int n_in,
                              void* d_out, int out_size, void* d_ws, size_t ws_size,
                              hipStream_t stream) {
    const float* x = (const float*)d_in[0];
    const float* signs = (const float*)d_in[1];
    float* out = (float*)d_out;
    const int B = in_sizes[0] / D;  // 16384 rows
    rht_kernel<<<dim3(B), dim3(NT), 0, stream>>>(x, signs, out);
}